// Round 12
// baseline (167.804 us; speedup 1.0000x reference)
//
#include <hip/hip_runtime.h>
#include <hip/hip_bf16.h>

typedef unsigned char u8;
typedef float f32x4 __attribute__((ext_vector_type(4)));
typedef unsigned u32x4 __attribute__((ext_vector_type(4)));
typedef int i32x4 __attribute__((ext_vector_type(4)));
typedef int i32x8 __attribute__((ext_vector_type(8)));

#define NB 4096     // batch rows
#define NM 16384    // memory bank rows
#define ND 256      // feature dim (K)
#define CT 160      // col tiles (20480 / 128)
#define RT 32       // row tiles (4096 / 128)
#define EPAD 132    // transpose-reduce row stride (floats); 132*4=528 keeps 16B align
#define FB 64       // finalize blocks (64 rows each)

__device__ __forceinline__ float ex2(float x) {
#if __has_builtin(__builtin_amdgcn_exp2f)
    return __builtin_amdgcn_exp2f(x);   // single v_exp_f32
#else
    return exp2f(x);
#endif
}

__device__ __forceinline__ float lg2(float x) {
#if __has_builtin(__builtin_amdgcn_logf)
    return __builtin_amdgcn_logf(x);    // single v_log_f32 (log2)
#else
    return __log2f(x);
#endif
}

// float4 -> 4 packed OCP e4m3 bytes (v_cvt_pk_fp8_f32, gfx940+)
__device__ __forceinline__ int f4_to_fp8x4(float4 v) {
    int r = __builtin_amdgcn_cvt_pk_fp8_f32(v.x, v.y, 0, false);   // bytes 0,1
    r = __builtin_amdgcn_cvt_pk_fp8_f32(v.z, v.w, r, true);        // bytes 2,3
    return r;
}

__device__ __forceinline__ void gld_lds16(const u8* g, u8* l) {
    __builtin_amdgcn_global_load_lds((__attribute__((address_space(1))) void*)g,
                                     (__attribute__((address_space(3))) void*)l,
                                     16, 0, 0);
}

// ---- fused prep: normalize f1/f2 (fp32 + fp8*kl + fp8 unscaled), banks ----
// Features: fp8 copy PRE-SCALED by kl = scale*log2e (A-side of every tile)
// AND an UNSCALED fp8 copy (B-side of feature-vs-feature tiles) -> gemm
// acc == kl*s for ALL tiles. blocks 0..2047: feature rows (4 rows/block).
// blocks 2048..4095: bank conversion, 4 float4/thread coalesced.
__global__ __launch_bounds__(256) void prep(
    const float* __restrict__ if1, const float* __restrict__ if2,
    const float* __restrict__ mb1, const float* __restrict__ mb2,
    const float* __restrict__ scale_ptr,
    float* __restrict__ f1f, float* __restrict__ f2f,
    u8* __restrict__ f1n, u8* __restrict__ f2n,
    u8* __restrict__ f1u, u8* __restrict__ f2u,
    u8* __restrict__ mb1n, u8* __restrict__ mb2n,
    unsigned* __restrict__ Mpack, float* __restrict__ accum)
{
    const int b = blockIdx.x, t = threadIdx.x;
    if (b == 0 && t < 8) accum[t] = 0.f;        // (legacy slots, unused sums)
    if (b < 32) Mpack[b * 256 + t] = 0u;        // [2*NB] = 8192 for atomicMax
    if (b < 2048) {
        const int wave = t >> 6, lane = t & 63;
        const int g = b * 4 + wave;         // 0..8191
        const float* in; float* of; u8* ob; u8* obu; int row;
        if (g < NB) { in = if1; of = f1f; ob = f1n; obu = f1u; row = g; }
        else        { in = if2; of = f2f; ob = f2n; obu = f2u; row = g - NB; }
        float4 v = ((const float4*)(in + (size_t)row * ND))[lane];
        float ss = v.x*v.x + v.y*v.y + v.z*v.z + v.w*v.w;
        #pragma unroll
        for (int off = 1; off < 64; off <<= 1) ss += __shfl_xor(ss, off, 64);
        float inv = 1.0f / fmaxf(sqrtf(ss), 1e-12f);
        float4 o = make_float4(v.x*inv, v.y*inv, v.z*inv, v.w*inv);
        ((float4*)(of + (size_t)row * ND))[lane] = o;      // fp32 unscaled
        ((int*)obu)[row * 64 + lane] = f4_to_fp8x4(o);     // fp8 UNSCALED
        const float kl = scale_ptr[0] * 1.44269504088896f;
        float4 ok = make_float4(o.x*kl, o.y*kl, o.z*kl, o.w*kl);
        ((int*)ob)[row * 64 + lane] = f4_to_fp8x4(ok);     // fp8 SCALED
    } else {
        // banks: 2*NM*64 = 2,097,152 float4s over 2048 blocks x 256 thr x 4
        const size_t base = (size_t)(b - 2048) * 1024 + t;
        #pragma unroll
        for (int k = 0; k < 4; ++k) {
            size_t i = base + (size_t)k * 256;
            const float* in; u8* ob; size_t idx;
            if (i < (size_t)NM * 64) { in = mb1; ob = mb1n; idx = i; }
            else { in = mb2; ob = mb2n; idx = i - (size_t)NM * 64; }
            float4 v = ((const float4*)in)[idx];
            ((int*)ob)[idx] = f4_to_fp8x4(v);
        }
    }
}

// ---- fused GEMM (MX-fp8 K=256) + (sum-exp, packed max/argmax) epilogue -----
// grid: (160 coltiles, 32 rowtiles, 2 matmuls), block 256 (4 waves, 2x2).
// Block tile 128x128, fp8 e4m3 inputs, mfma_scale_f32_16x16x128_f8f6f4 with
// unit scales. K staged in 2 chunks of 128 B/row, XOR-swizzled LDS.
// R12 = R6/R10's verified best hot path, byte-identical.
// Lessons (all measured): (256,4)@128x128 spills (R2); 512-thr dbuf (R3),
// 128x64 tile (R5), no-LDS direct-global (R7), swapped-operand in-reg
// epilogue (R8) all regressed; fused finalize with per-block __threadfence
// (R9) serialized ~10K L2 writebacks -> 13x slowdown. Producer->consumer
// stages MUST stay separate kernels (one bulk flush at the boundary).
// The 5.24M SQ_LDS_BANK_CONFLICT is K-loop ds_read_b128 phase cost
// (R7 measured 0 with K-loop LDS removed); epilogue LDS is conflict-free.
__global__ __launch_bounds__(256, 3) void gemm_nce(
    const u8* __restrict__ f1n, const u8* __restrict__ f2n,
    const u8* __restrict__ f1u, const u8* __restrict__ f2u,
    const u8* __restrict__ mb1n, const u8* __restrict__ mb2n,
    const float* __restrict__ scale_ptr,
    float* __restrict__ Zpart,      // [2][CT][NB]
    unsigned* __restrict__ Mpack)   // [2][NB]
{
    __shared__ __attribute__((aligned(16))) u8 smem[2 * 32 * EPAD * 4]; // 33792 B
    u8* As = smem;                  // 16 KB tile (dead after K loop)
    u8* Bs = smem + 16384;          // 16 KB tile (dead after K loop)
    float*    eT = (float*)smem;                      // [32][EPAD] fp32
    unsigned* pT = (unsigned*)(smem + 32 * EPAD * 4); // [32][EPAD] u32

    const int ctile = blockIdx.x, rtile = blockIdx.y, z = blockIdx.z;
    const u8* A  = (z ? f2n : f1n) + (size_t)rtile * 128 * ND;
    const u8* Bp = (ctile < 32) ? ((z ? f1u : f2u) + (size_t)ctile * 128 * ND)
                                 : ((z ? mb1n : mb2n) + (size_t)(ctile - 32) * 128 * ND);
    const int t = threadIdx.x;
    const int wave = t >> 6, lane = t & 63;
    const int wr = wave >> 1, wc = wave & 1;
    const int lane16 = lane & 15, q = lane >> 4;
    const int srow = t >> 3;                        // 0..31 staged row
    const int cg = (t & 7) ^ (srow & 7);            // swizzled global chunk

    f32x4 acc[4][4] = {};

    #pragma unroll
    for (int kt = 0; kt < 2; ++kt) {
        const u8* ga = A  + (size_t)srow * ND + kt * 128 + cg * 16;
        const u8* gb = Bp + (size_t)srow * ND + kt * 128 + cg * 16;
        u8* la = As + t * 16;
        u8* lb = Bs + t * 16;
        #pragma unroll
        for (int ch = 0; ch < 4; ++ch) {    // 128 rows in 32-row strides
            gld_lds16(ga + (size_t)ch * 32 * ND, la + ch * 4096);
            gld_lds16(gb + (size_t)ch * 32 * ND, lb + ch * 4096);
        }
        __syncthreads();   // drains vmcnt (global_load_lds) before LDS reads
        {
            i32x8 b8[4];
            #pragma unroll
            for (int j = 0; j < 4; ++j) {
                int rb = wc*64 + j*16 + lane16;
                const u8* pb = Bs + rb * 128;
                int s0 = (2*q) ^ (rb & 7);
                i32x4 lo = *(const i32x4*)(pb + s0*16);
                i32x4 hi = *(const i32x4*)(pb + (s0^1)*16);
                b8[j] = (i32x8){lo[0],lo[1],lo[2],lo[3],hi[0],hi[1],hi[2],hi[3]};
            }
            #pragma unroll
            for (int i = 0; i < 4; ++i) {
                int ra = wr*64 + i*16 + lane16;
                const u8* pa = As + ra * 128;
                int s0 = (2*q) ^ (ra & 7);
                i32x4 lo = *(const i32x4*)(pa + s0*16);
                i32x4 hi = *(const i32x4*)(pa + (s0^1)*16);
                i32x8 a8 = (i32x8){lo[0],lo[1],lo[2],lo[3],hi[0],hi[1],hi[2],hi[3]};
                #pragma unroll
                for (int j = 0; j < 4; ++j)
                    acc[i][j] = __builtin_amdgcn_mfma_scale_f32_16x16x128_f8f6f4(
                        a8, b8[j], acc[i][j], 0, 0,
                        0, 0x7F7F7F7F, 0, 0x7F7F7F7F);   // unit e8m0 scales
            }
        }
        __syncthreads();
    }
    // tiles dead; eT/pT live in smem from here on.

    const bool doicel = (ctile >= 32);

    const int colg = wc * 16 + lane16;           // colgroup 0..31
    float*    eTc = eT + colg * EPAD;
    unsigned* pTc = pT + colg * EPAD;

    unsigned cpack[4];
    #pragma unroll
    for (int j = 0; j < 4; ++j) cpack[j] = 127 - (wc*64 + j*16 + lane16);

    // C/D layout (m89/m91, dtype-independent): col = lane&15, row = q*4 + r
    // acc == t = kl*s for ALL tiles (A scaled, B unscaled).
    #pragma unroll
    for (int i = 0; i < 4; ++i) {
        const int rowb = wr*64 + i*16 + q*4;
        f32x4 ev; u32x4 pv;
        #pragma unroll
        for (int r = 0; r < 4; ++r) {
            float e0 = ex2(acc[i][0][r]), e1 = ex2(acc[i][1][r]),
                  e2 = ex2(acc[i][2][r]), e3 = ex2(acc[i][3][r]);
            ev[r] = (e0 + e1) + (e2 + e3);
            if (doicel) {
                // exp bits are order-preserving (positive); low 7 bits -> col
                unsigned p0 = (__float_as_uint(e0) & 0xFFFFFF80u) | cpack[0];
                unsigned p1 = (__float_as_uint(e1) & 0xFFFFFF80u) | cpack[1];
                unsigned p2 = (__float_as_uint(e2) & 0xFFFFFF80u) | cpack[2];
                unsigned p3 = (__float_as_uint(e3) & 0xFFFFFF80u) | cpack[3];
                pv[r] = max(max(p0, p1), max(p2, p3));
            }
        }
        *(f32x4*)(eTc + rowb) = ev;              // 16B-aligned (rowb%4==0)
        if (doicel) *(u32x4*)(pTc + rowb) = pv;
    }
    __syncthreads();

    if (t < 128) {
        // waves 0-1: Z row-sums over 32 colgroups, 4 independent partials
        float s0 = 0.f, s1 = 0.f, s2 = 0.f, s3 = 0.f;
        #pragma unroll
        for (int c4 = 0; c4 < 32; c4 += 4) {
            s0 += eT[(c4+0)*EPAD + t];
            s1 += eT[(c4+1)*EPAD + t];
            s2 += eT[(c4+2)*EPAD + t];
            s3 += eT[(c4+3)*EPAD + t];
        }
        Zpart[((size_t)z * CT + ctile) * NB + rtile*128 + t] = (s0+s1)+(s2+s3);
    } else if (doicel) {
        // waves 2-3: packed max over 32 colgroups, decode, one atomicMax/row
        const int row = t - 128;
        unsigned m0 = 0u, m1 = 0u;
        #pragma unroll
        for (int c2 = 0; c2 < 32; c2 += 2) {
            m0 = max(m0, pT[(c2+0)*EPAD + row]);
            m1 = max(m1, pT[(c2+1)*EPAD + row]);
        }
        unsigned m = max(m0, m1);
        int cl = 127 - (int)(m & 127u);          // col within 128-tile
        unsigned g = (m & 0xFFFFC000u) |
                     (unsigned)(16383 - ((ctile - 32)*128 + cl));
        atomicMax(&Mpack[z * NB + rtile*128 + row], g);
    }
}

// ---- finalize: Z-reduce + decode argmax + gather + MSE/CE, NO ATOMICS -----
// R12: 64 blocks x 256 threads, 64 rows/block (4 passes of the verified
// 16-row body). Each block writes its 5 partial sums NON-atomically to a
// private slot accum[16 + bid*8 + j]. R9-vs-R10 timing isolated finalize4
// at ~51us; mechanism = 1280 device-scope same-cacheline atomicAdds
// (256 blocks x 5) serializing at the coherence point (~40ns each).
// Private slots + a separate 1-wave combine kernel remove ALL contention
// and ALL device fences (kernel boundary = the one bulk flush; R9 lesson).
__global__ __launch_bounds__(256) void finalize4(
    const float* __restrict__ Zpart, const unsigned* __restrict__ Mpack,
    const float* __restrict__ f1f, const float* __restrict__ f2f,
    const float* __restrict__ mb1, const float* __restrict__ mb2,
    const float* __restrict__ scale_ptr, float* __restrict__ accum)
{
    __shared__ float zp[2][16][16];   // [z][cidx][row_l]
    __shared__ float Zr[2][16];
    __shared__ float lds5[16][5];
    const int t = threadIdx.x, g = t >> 4, l16 = t & 15;
    const float scale = *scale_ptr;
    const float kl = scale * 1.44269504088896f;
    float acc5 = 0.f;                 // per-thread partial (t<5 meaningful)

    for (int p = 0; p < 4; ++p) {
        const int base = blockIdx.x * 64 + p * 16;

        // Phase A: Z partial sums, coalesced (lanes along rows)
        {
            const int row_l = t & 15, cidx = t >> 4;
            #pragma unroll
            for (int z = 0; z < 2; ++z) {
                float s = 0.f;
                #pragma unroll
                for (int c = cidx * 10; c < cidx * 10 + 10; ++c)
                    s += Zpart[((size_t)z * CT + c) * NB + base + row_l];
                zp[z][cidx][row_l] = s;
            }
        }
        __syncthreads();
        if (t < 32) {
            int z = t >> 4, rl = t & 15;
            float s = 0.f;
            #pragma unroll
            for (int k = 0; k < 16; ++k) s += zp[z][k][rl];
            Zr[z][rl] = s;
        }
        __syncthreads();

        const int row = base + g;
        unsigned mp1 = Mpack[row], mp2 = Mpack[NB + row];
        int a1 = 16383 - (int)(mp1 & 16383u);
        int a2 = 16383 - (int)(mp2 & 16383u);
        float m1 = lg2(__uint_as_float(mp1 & 0xFFFFC000u)) / kl;
        float m2 = lg2(__uint_as_float(mp2 & 0xFFFFC000u)) / kl;

        const float4* x1p = (const float4*)(f1f + (size_t)row * ND);
        const float4* x2p = (const float4*)(f2f + (size_t)row * ND);
        const float4* y1p = (const float4*)(mb2 + (size_t)a1 * ND);
        const float4* y2p = (const float4*)(mb1 + (size_t)a2 * ND);
        float d = 0.f, sq1 = 0.f, sq2 = 0.f;
        #pragma unroll
        for (int k = 0; k < 4; ++k) {
            int idx = k * 16 + l16;
            float4 x1 = x1p[idx], x2 = x2p[idx], y1 = y1p[idx], y2 = y2p[idx];
            d += x1.x*x2.x + x1.y*x2.y + x1.z*x2.z + x1.w*x2.w;
            float dx = x1.x-y1.x, dy = x1.y-y1.y, dz = x1.z-y1.z, dw = x1.w-y1.w;
            sq1 += dx*dx + dy*dy + dz*dz + dw*dw;
            dx = x2.x-y2.x; dy = x2.y-y2.y; dz = x2.z-y2.z; dw = x2.w-y2.w;
            sq2 += dx*dx + dy*dy + dz*dz + dw*dw;
        }
        #pragma unroll
        for (int off = 1; off < 16; off <<= 1) {
            d   += __shfl_xor(d,   off, 16);
            sq1 += __shfl_xor(sq1, off, 16);
            sq2 += __shfl_xor(sq2, off, 16);
        }
        if (l16 == 0) {
            bool k1 = m1 > 0.2f, k2 = m2 > 0.2f;
            lds5[g][0] = logf(Zr[0][g]) + logf(Zr[1][g]) - 2.f * scale * d;
            lds5[g][1] = k1 ? sq1 : 0.f;
            lds5[g][2] = k1 ? 1.f : 0.f;
            lds5[g][3] = k2 ? sq2 : 0.f;
            lds5[g][4] = k2 ? 1.f : 0.f;
        }
        __syncthreads();
        if (t < 5) {
            float s = 0.f;
            #pragma unroll
            for (int r = 0; r < 16; ++r) s += lds5[r][t];
            acc5 += s;
        }
        __syncthreads();              // zp/lds5 reusable next pass
    }
    if (t < 5) accum[16 + blockIdx.x * 8 + t] = acc5;   // private slot
}

// ---- combine: 1 wave sums the 64x5 partials and writes the scalar --------
__global__ __launch_bounds__(64) void combine(
    const float* __restrict__ accum, float* __restrict__ out)
{
    const int t = threadIdx.x;        // t = block index 0..63
    float v[5];
    #pragma unroll
    for (int j = 0; j < 5; ++j) v[j] = accum[16 + t * 8 + j];
    #pragma unroll
    for (int j = 0; j < 5; ++j)
        #pragma unroll
        for (int off = 1; off < 64; off <<= 1)
            v[j] += __shfl_xor(v[j], off, 64);
    if (t == 0) {
        float nce = 0.5f * v[0] / (float)NB;
        float icel1 = v[2] > 0.f ? v[1] / (v[2] * (float)ND) : 0.f;
        float icel2 = v[4] > 0.f ? v[3] / (v[4] * (float)ND) : 0.f;
        out[0] = nce + 0.25f * (icel1 + icel2);   // LAMBDA_ICEL = 0.5
    }
}

extern "C" void kernel_launch(void* const* d_in, const int* in_sizes, int n_in,
                              void* d_out, int out_size, void* d_ws, size_t ws_size,
                              hipStream_t stream) {
    const float* if1   = (const float*)d_in[0];
    const float* if2   = (const float*)d_in[1];
    const float* scale = (const float*)d_in[2];
    const float* mb1   = (const float*)d_in[3];
    const float* mb2   = (const float*)d_in[4];
    float* out = (float*)d_out;

    unsigned char* w = (unsigned char*)d_ws;
    size_t off = 0;
    auto alloc = [&](size_t bytes) {
        void* p = w + off;
        off += (bytes + 255) & ~(size_t)255;
        return p;
    };
    u8*       f1n   = (u8*)      alloc((size_t)NB * ND);
    u8*       f2n   = (u8*)      alloc((size_t)NB * ND);
    u8*       f1u   = (u8*)      alloc((size_t)NB * ND);
    u8*       f2u   = (u8*)      alloc((size_t)NB * ND);
    u8*       mb1n  = (u8*)      alloc((size_t)NM * ND);
    u8*       mb2n  = (u8*)      alloc((size_t)NM * ND);
    float*    f1f   = (float*)   alloc((size_t)NB * ND * 4);
    float*    f2f   = (float*)   alloc((size_t)NB * ND * 4);
    float*    Zpart = (float*)   alloc((size_t)2 * CT * NB * 4);
    unsigned* Mpack = (unsigned*)alloc((size_t)2 * NB * 4);
    float*    accum = (float*)   alloc(4096);   // [16 + FB*8] partial slots

    prep<<<dim3(4096), 256, 0, stream>>>(if1, if2, mb1, mb2, scale,
                                         f1f, f2f, f1n, f2n, f1u, f2u,
                                         mb1n, mb2n, Mpack, accum);
    gemm_nce<<<dim3(CT, RT, 2), 256, 0, stream>>>(f1n, f2n, f1u, f2u,
                                                  mb1n, mb2n, scale,
                                                  Zpart, Mpack);
    finalize4<<<dim3(FB), 256, 0, stream>>>(Zpart, Mpack,
                                            f1f, f2f, mb1, mb2, scale,
                                            accum);
    combine<<<dim3(1), 64, 0, stream>>>(accum, out);
}

// Round 13
// 162.399 us; speedup vs baseline: 1.0333x; 1.0333x over previous
//
#include <hip/hip_runtime.h>
#include <hip/hip_bf16.h>

typedef unsigned char u8;
typedef float f32x4 __attribute__((ext_vector_type(4)));
typedef unsigned u32x4 __attribute__((ext_vector_type(4)));
typedef int i32x4 __attribute__((ext_vector_type(4)));
typedef int i32x8 __attribute__((ext_vector_type(8)));

#define NB 4096     // batch rows
#define NM 16384    // memory bank rows
#define ND 256      // feature dim (K)
#define CT 160      // col tiles (20480 / 128)
#define RT 32       // row tiles (4096 / 128)
#define EPAD 132    // transpose-reduce row stride (floats); 132*4=528 keeps 16B align

__device__ __forceinline__ float ex2(float x) {
#if __has_builtin(__builtin_amdgcn_exp2f)
    return __builtin_amdgcn_exp2f(x);   // single v_exp_f32
#else
    return exp2f(x);
#endif
}

__device__ __forceinline__ float lg2(float x) {
#if __has_builtin(__builtin_amdgcn_logf)
    return __builtin_amdgcn_logf(x);    // single v_log_f32 (log2)
#else
    return __log2f(x);
#endif
}

// float4 -> 4 packed OCP e4m3 bytes (v_cvt_pk_fp8_f32, gfx940+)
__device__ __forceinline__ int f4_to_fp8x4(float4 v) {
    int r = __builtin_amdgcn_cvt_pk_fp8_f32(v.x, v.y, 0, false);   // bytes 0,1
    r = __builtin_amdgcn_cvt_pk_fp8_f32(v.z, v.w, r, true);        // bytes 2,3
    return r;
}

__device__ __forceinline__ void gld_lds16(const u8* g, u8* l) {
    __builtin_amdgcn_global_load_lds((__attribute__((address_space(1))) void*)g,
                                     (__attribute__((address_space(3))) void*)l,
                                     16, 0, 0);
}

// ---- fused prep: normalize f1/f2 (fp32 + fp8*kl + fp8 unscaled), banks ----
// Features: fp8 copy PRE-SCALED by kl = scale*log2e (A-side of every tile)
// AND an UNSCALED fp8 copy (B-side of feature-vs-feature tiles) -> gemm
// acc == kl*s for ALL tiles. blocks 0..2047: feature rows (4 rows/block).
// blocks 2048..4095: bank conversion, 4 float4/thread coalesced.
__global__ __launch_bounds__(256) void prep(
    const float* __restrict__ if1, const float* __restrict__ if2,
    const float* __restrict__ mb1, const float* __restrict__ mb2,
    const float* __restrict__ scale_ptr,
    float* __restrict__ f1f, float* __restrict__ f2f,
    u8* __restrict__ f1n, u8* __restrict__ f2n,
    u8* __restrict__ f1u, u8* __restrict__ f2u,
    u8* __restrict__ mb1n, u8* __restrict__ mb2n,
    unsigned* __restrict__ Mpack, float* __restrict__ accum)
{
    const int b = blockIdx.x, t = threadIdx.x;
    if (b == 0 && t < 8) accum[t] = 0.f;        // sums + counter
    if (b < 32) Mpack[b * 256 + t] = 0u;        // [2*NB] = 8192 for atomicMax
    if (b < 2048) {
        const int wave = t >> 6, lane = t & 63;
        const int g = b * 4 + wave;         // 0..8191
        const float* in; float* of; u8* ob; u8* obu; int row;
        if (g < NB) { in = if1; of = f1f; ob = f1n; obu = f1u; row = g; }
        else        { in = if2; of = f2f; ob = f2n; obu = f2u; row = g - NB; }
        float4 v = ((const float4*)(in + (size_t)row * ND))[lane];
        float ss = v.x*v.x + v.y*v.y + v.z*v.z + v.w*v.w;
        #pragma unroll
        for (int off = 1; off < 64; off <<= 1) ss += __shfl_xor(ss, off, 64);
        float inv = 1.0f / fmaxf(sqrtf(ss), 1e-12f);
        float4 o = make_float4(v.x*inv, v.y*inv, v.z*inv, v.w*inv);
        ((float4*)(of + (size_t)row * ND))[lane] = o;      // fp32 unscaled
        ((int*)obu)[row * 64 + lane] = f4_to_fp8x4(o);     // fp8 UNSCALED
        const float kl = scale_ptr[0] * 1.44269504088896f;
        float4 ok = make_float4(o.x*kl, o.y*kl, o.z*kl, o.w*kl);
        ((int*)ob)[row * 64 + lane] = f4_to_fp8x4(ok);     // fp8 SCALED
    } else {
        // banks: 2*NM*64 = 2,097,152 float4s over 2048 blocks x 256 thr x 4
        const size_t base = (size_t)(b - 2048) * 1024 + t;
        #pragma unroll
        for (int k = 0; k < 4; ++k) {
            size_t i = base + (size_t)k * 256;
            const float* in; u8* ob; size_t idx;
            if (i < (size_t)NM * 64) { in = mb1; ob = mb1n; idx = i; }
            else { in = mb2; ob = mb2n; idx = i - (size_t)NM * 64; }
            float4 v = ((const float4*)in)[idx];
            ((int*)ob)[idx] = f4_to_fp8x4(v);
        }
    }
}

// ---- fused GEMM (MX-fp8 K=256) + (sum-exp, packed max/argmax) epilogue -----
// grid: (160 coltiles, 32 rowtiles, 2 matmuls), block 256 (4 waves, 2x2).
// Block tile 128x128, fp8 e4m3 inputs, mfma_scale_f32_16x16x128_f8f6f4 with
// unit scales. K staged in 2 chunks of 128 B/row, XOR-swizzled LDS.
// R13: feature-x-feature dedup. exp(T_ij) (T = kl*f1_i.f2_j) feeds BOTH
// Z12 row-sums and Z21 col-sums, so z=0/ctile<32 blocks now produce both:
// row-sums via the verified eT transpose path (unchanged), col-sums
// in-register (rows are lane-local: 48 adds + 8 shfl_xor + 1KB LDS combine
// in the dead pT buffer) -> Zpart[1][rtile][ctile*128+n]. z=1/ctile<32
// blocks early-return: 1024 of 10240 full blocks become no-ops (-10%).
// Lessons (all measured): (256,4)@128x128 spills (R2); 512-thr dbuf (R3),
// 128x64 tile (R5), no-LDS (R7), global swapped-operand epilogue (R8),
// per-block __threadfence fusion (R9, 13x), atomic-free 64-blk finalize
// (R12, null) all regressed or null. 5.24M bank-conflict = K-loop
// ds_read_b128 phase cost (R7: 0 without K-loop LDS); epilogue LDS free.
__global__ __launch_bounds__(256, 3) void gemm_nce(
    const u8* __restrict__ f1n, const u8* __restrict__ f2n,
    const u8* __restrict__ f1u, const u8* __restrict__ f2u,
    const u8* __restrict__ mb1n, const u8* __restrict__ mb2n,
    const float* __restrict__ scale_ptr,
    float* __restrict__ Zpart,      // [2][CT][NB]
    unsigned* __restrict__ Mpack)   // [2][NB]
{
    __shared__ __attribute__((aligned(16))) u8 smem[2 * 32 * EPAD * 4]; // 33792 B
    u8* As = smem;                  // 16 KB tile (dead after K loop)
    u8* Bs = smem + 16384;          // 16 KB tile (dead after K loop)
    float*    eT = (float*)smem;                      // [32][EPAD] fp32
    unsigned* pT = (unsigned*)(smem + 32 * EPAD * 4); // [32][EPAD] u32

    const int ctile = blockIdx.x, rtile = blockIdx.y, z = blockIdx.z;
    if (z == 1 && ctile < 32) return;   // R13: transpose of z=0 feature tile

    const u8* A  = (z ? f2n : f1n) + (size_t)rtile * 128 * ND;
    const u8* Bp = (ctile < 32) ? ((z ? f1u : f2u) + (size_t)ctile * 128 * ND)
                                 : ((z ? mb1n : mb2n) + (size_t)(ctile - 32) * 128 * ND);
    const int t = threadIdx.x;
    const int wave = t >> 6, lane = t & 63;
    const int wr = wave >> 1, wc = wave & 1;
    const int lane16 = lane & 15, q = lane >> 4;
    const int srow = t >> 3;                        // 0..31 staged row
    const int cg = (t & 7) ^ (srow & 7);            // swizzled global chunk

    f32x4 acc[4][4] = {};

    #pragma unroll
    for (int kt = 0; kt < 2; ++kt) {
        const u8* ga = A  + (size_t)srow * ND + kt * 128 + cg * 16;
        const u8* gb = Bp + (size_t)srow * ND + kt * 128 + cg * 16;
        u8* la = As + t * 16;
        u8* lb = Bs + t * 16;
        #pragma unroll
        for (int ch = 0; ch < 4; ++ch) {    // 128 rows in 32-row strides
            gld_lds16(ga + (size_t)ch * 32 * ND, la + ch * 4096);
            gld_lds16(gb + (size_t)ch * 32 * ND, lb + ch * 4096);
        }
        __syncthreads();   // drains vmcnt (global_load_lds) before LDS reads
        {
            i32x8 b8[4];
            #pragma unroll
            for (int j = 0; j < 4; ++j) {
                int rb = wc*64 + j*16 + lane16;
                const u8* pb = Bs + rb * 128;
                int s0 = (2*q) ^ (rb & 7);
                i32x4 lo = *(const i32x4*)(pb + s0*16);
                i32x4 hi = *(const i32x4*)(pb + (s0^1)*16);
                b8[j] = (i32x8){lo[0],lo[1],lo[2],lo[3],hi[0],hi[1],hi[2],hi[3]};
            }
            #pragma unroll
            for (int i = 0; i < 4; ++i) {
                int ra = wr*64 + i*16 + lane16;
                const u8* pa = As + ra * 128;
                int s0 = (2*q) ^ (ra & 7);
                i32x4 lo = *(const i32x4*)(pa + s0*16);
                i32x4 hi = *(const i32x4*)(pa + (s0^1)*16);
                i32x8 a8 = (i32x8){lo[0],lo[1],lo[2],lo[3],hi[0],hi[1],hi[2],hi[3]};
                #pragma unroll
                for (int j = 0; j < 4; ++j)
                    acc[i][j] = __builtin_amdgcn_mfma_scale_f32_16x16x128_f8f6f4(
                        a8, b8[j], acc[i][j], 0, 0,
                        0, 0x7F7F7F7F, 0, 0x7F7F7F7F);   // unit e8m0 scales
            }
        }
        __syncthreads();
    }
    // tiles dead; eT/pT live in smem from here on.

    const bool doicel = (ctile >= 32);

    const int colg = wc * 16 + lane16;           // colgroup 0..31
    float*    eTc = eT + colg * EPAD;
    unsigned* pTc = pT + colg * EPAD;
    float*    colZ = (float*)pT;                 // feat tiles: [2][128] colsums

    unsigned cpack[4];
    #pragma unroll
    for (int j = 0; j < 4; ++j) cpack[j] = 127 - (wc*64 + j*16 + lane16);

    // C/D layout (m89/m91, dtype-independent): col = lane&15, row = q*4 + r
    // acc == t = kl*s for ALL tiles (A scaled, B unscaled).
    float cz0 = 0.f, cz1 = 0.f, cz2 = 0.f, cz3 = 0.f;   // feat col-sums
    #pragma unroll
    for (int i = 0; i < 4; ++i) {
        const int rowb = wr*64 + i*16 + q*4;
        f32x4 ev; u32x4 pv;
        #pragma unroll
        for (int r = 0; r < 4; ++r) {
            float e0 = ex2(acc[i][0][r]), e1 = ex2(acc[i][1][r]),
                  e2 = ex2(acc[i][2][r]), e3 = ex2(acc[i][3][r]);
            ev[r] = (e0 + e1) + (e2 + e3);
            if (doicel) {
                // exp bits are order-preserving (positive); low 7 bits -> col
                unsigned p0 = (__float_as_uint(e0) & 0xFFFFFF80u) | cpack[0];
                unsigned p1 = (__float_as_uint(e1) & 0xFFFFFF80u) | cpack[1];
                unsigned p2 = (__float_as_uint(e2) & 0xFFFFFF80u) | cpack[2];
                unsigned p3 = (__float_as_uint(e3) & 0xFFFFFF80u) | cpack[3];
                pv[r] = max(max(p0, p1), max(p2, p3));
            } else {
                cz0 += e0; cz1 += e1; cz2 += e2; cz3 += e3;   // per-col over m
            }
        }
        *(f32x4*)(eTc + rowb) = ev;              // 16B-aligned (rowb%4==0)
        if (doicel) *(u32x4*)(pTc + rowb) = pv;
    }
    if (!doicel) {
        // reduce col-sums over q groups (rows q*4..q*4+3 per i)
        cz0 += __shfl_xor(cz0, 16, 64); cz0 += __shfl_xor(cz0, 32, 64);
        cz1 += __shfl_xor(cz1, 16, 64); cz1 += __shfl_xor(cz1, 32, 64);
        cz2 += __shfl_xor(cz2, 16, 64); cz2 += __shfl_xor(cz2, 32, 64);
        cz3 += __shfl_xor(cz3, 16, 64); cz3 += __shfl_xor(cz3, 32, 64);
        if (q == 0) {                    // lanes 0..15 hold wave-complete sums
            colZ[wr*128 + wc*64 +  0 + lane16] = cz0;
            colZ[wr*128 + wc*64 + 16 + lane16] = cz1;
            colZ[wr*128 + wc*64 + 32 + lane16] = cz2;
            colZ[wr*128 + wc*64 + 48 + lane16] = cz3;
        }
    }
    __syncthreads();

    if (t < 128) {
        // waves 0-1: Z row-sums over 32 colgroups, 4 independent partials
        float s0 = 0.f, s1 = 0.f, s2 = 0.f, s3 = 0.f;
        #pragma unroll
        for (int c4 = 0; c4 < 32; c4 += 4) {
            s0 += eT[(c4+0)*EPAD + t];
            s1 += eT[(c4+1)*EPAD + t];
            s2 += eT[(c4+2)*EPAD + t];
            s3 += eT[(c4+3)*EPAD + t];
        }
        Zpart[((size_t)z * CT + ctile) * NB + rtile*128 + t] = (s0+s1)+(s2+s3);
        if (!doicel) {                   // Z21 partial from the same tile
            float c = colZ[t] + colZ[128 + t];
            Zpart[((size_t)CT + rtile) * NB + ctile*128 + t] = c;
        }
    } else if (doicel) {
        // waves 2-3: packed max over 32 colgroups, decode, one atomicMax/row
        const int row = t - 128;
        unsigned m0 = 0u, m1 = 0u;
        #pragma unroll
        for (int c2 = 0; c2 < 32; c2 += 2) {
            m0 = max(m0, pT[(c2+0)*EPAD + row]);
            m1 = max(m1, pT[(c2+1)*EPAD + row]);
        }
        unsigned m = max(m0, m1);
        int cl = 127 - (int)(m & 127u);          // col within 128-tile
        unsigned g = (m & 0xFFFFC000u) |
                     (unsigned)(16383 - ((ctile - 32)*128 + cl));
        atomicMax(&Mpack[z * NB + rtile*128 + row], g);
    }
}

// ---- finalize: Z-reduce + decode argmax + gather + MSE/CE + combine --------
// 256 blocks x 256 threads: 16 rows/block. (fp32 banks -> exact MSE/diag.)
// Packed max decodes via hardware log2: sim = log2(e_max)/kl.
// (R10's verified version; R12's atomic-free variant measured null/worse.)
__global__ __launch_bounds__(256) void finalize4(
    const float* __restrict__ Zpart, const unsigned* __restrict__ Mpack,
    const float* __restrict__ f1f, const float* __restrict__ f2f,
    const float* __restrict__ mb1, const float* __restrict__ mb2,
    const float* __restrict__ scale_ptr, float* __restrict__ accum,
    float* __restrict__ out)
{
    __shared__ float zp[2][16][16];   // [z][cidx][row_l]
    __shared__ float Zr[2][16];
    __shared__ float lds5[16][5];
    const int t = threadIdx.x, g = t >> 4, l16 = t & 15;
    const int base = blockIdx.x * 16;

    // Phase A: Z partial sums, coalesced (lanes along rows)
    {
        const int row_l = t & 15, cidx = t >> 4;
        #pragma unroll
        for (int z = 0; z < 2; ++z) {
            float s = 0.f;
            #pragma unroll
            for (int c = cidx * 10; c < cidx * 10 + 10; ++c)
                s += Zpart[((size_t)z * CT + c) * NB + base + row_l];
            zp[z][cidx][row_l] = s;
        }
    }
    __syncthreads();
    if (t < 32) {
        int z = t >> 4, rl = t & 15;
        float s = 0.f;
        #pragma unroll
        for (int k = 0; k < 16; ++k) s += zp[z][k][rl];
        Zr[z][rl] = s;
    }
    __syncthreads();

    const int row = base + g;
    const float scale = *scale_ptr;
    const float kl = scale * 1.44269504088896f;

    unsigned mp1 = Mpack[row], mp2 = Mpack[NB + row];
    int a1 = 16383 - (int)(mp1 & 16383u);
    int a2 = 16383 - (int)(mp2 & 16383u);
    float m1 = lg2(__uint_as_float(mp1 & 0xFFFFC000u)) / kl;
    float m2 = lg2(__uint_as_float(mp2 & 0xFFFFC000u)) / kl;

    const float4* x1p = (const float4*)(f1f + (size_t)row * ND);
    const float4* x2p = (const float4*)(f2f + (size_t)row * ND);
    const float4* y1p = (const float4*)(mb2 + (size_t)a1 * ND);
    const float4* y2p = (const float4*)(mb1 + (size_t)a2 * ND);
    float d = 0.f, sq1 = 0.f, sq2 = 0.f;
    #pragma unroll
    for (int k = 0; k < 4; ++k) {
        int idx = k * 16 + l16;
        float4 x1 = x1p[idx], x2 = x2p[idx], y1 = y1p[idx], y2 = y2p[idx];
        d += x1.x*x2.x + x1.y*x2.y + x1.z*x2.z + x1.w*x2.w;
        float dx = x1.x-y1.x, dy = x1.y-y1.y, dz = x1.z-y1.z, dw = x1.w-y1.w;
        sq1 += dx*dx + dy*dy + dz*dz + dw*dw;
        dx = x2.x-y2.x; dy = x2.y-y2.y; dz = x2.z-y2.z; dw = x2.w-y2.w;
        sq2 += dx*dx + dy*dy + dz*dz + dw*dw;
    }
    #pragma unroll
    for (int off = 1; off < 16; off <<= 1) {
        d   += __shfl_xor(d,   off, 16);
        sq1 += __shfl_xor(sq1, off, 16);
        sq2 += __shfl_xor(sq2, off, 16);
    }
    if (l16 == 0) {
        bool k1 = m1 > 0.2f, k2 = m2 > 0.2f;
        lds5[g][0] = logf(Zr[0][g]) + logf(Zr[1][g]) - 2.f * scale * d;
        lds5[g][1] = k1 ? sq1 : 0.f;
        lds5[g][2] = k1 ? 1.f : 0.f;
        lds5[g][3] = k2 ? sq2 : 0.f;
        lds5[g][4] = k2 ? 1.f : 0.f;
    }
    __syncthreads();
    if (t < 5) {
        float s = 0.f;
        #pragma unroll
        for (int r = 0; r < 16; ++r) s += lds5[r][t];
        atomicAdd(&accum[t], s);
    }
    __syncthreads();
    if (t == 0) {
        __threadfence();
        int old = atomicAdd((int*)(accum + 5), 1);
        if (old == (int)gridDim.x - 1) {        // last block: combine
            __threadfence();
            float a0 = atomicAdd(&accum[0], 0.f);
            float a1v = atomicAdd(&accum[1], 0.f);
            float a2v = atomicAdd(&accum[2], 0.f);
            float a3v = atomicAdd(&accum[3], 0.f);
            float a4v = atomicAdd(&accum[4], 0.f);
            float nce = 0.5f * a0 / (float)NB;
            float icel1 = a2v > 0.f ? a1v / (a2v * (float)ND) : 0.f;
            float icel2 = a4v > 0.f ? a3v / (a4v * (float)ND) : 0.f;
            out[0] = nce + 0.25f * (icel1 + icel2);   // LAMBDA_ICEL = 0.5
        }
    }
}

extern "C" void kernel_launch(void* const* d_in, const int* in_sizes, int n_in,
                              void* d_out, int out_size, void* d_ws, size_t ws_size,
                              hipStream_t stream) {
    const float* if1   = (const float*)d_in[0];
    const float* if2   = (const float*)d_in[1];
    const float* scale = (const float*)d_in[2];
    const float* mb1   = (const float*)d_in[3];
    const float* mb2   = (const float*)d_in[4];
    float* out = (float*)d_out;

    unsigned char* w = (unsigned char*)d_ws;
    size_t off = 0;
    auto alloc = [&](size_t bytes) {
        void* p = w + off;
        off += (bytes + 255) & ~(size_t)255;
        return p;
    };
    u8*       f1n   = (u8*)      alloc((size_t)NB * ND);
    u8*       f2n   = (u8*)      alloc((size_t)NB * ND);
    u8*       f1u   = (u8*)      alloc((size_t)NB * ND);
    u8*       f2u   = (u8*)      alloc((size_t)NB * ND);
    u8*       mb1n  = (u8*)      alloc((size_t)NM * ND);
    u8*       mb2n  = (u8*)      alloc((size_t)NM * ND);
    float*    f1f   = (float*)   alloc((size_t)NB * ND * 4);
    float*    f2f   = (float*)   alloc((size_t)NB * ND * 4);
    float*    Zpart = (float*)   alloc((size_t)2 * CT * NB * 4);
    unsigned* Mpack = (unsigned*)alloc((size_t)2 * NB * 4);
    float*    accum = (float*)   alloc(256);

    prep<<<dim3(4096), 256, 0, stream>>>(if1, if2, mb1, mb2, scale,
                                         f1f, f2f, f1n, f2n, f1u, f2u,
                                         mb1n, mb2n, Mpack, accum);
    gemm_nce<<<dim3(CT, RT, 2), 256, 0, stream>>>(f1n, f2n, f1u, f2u,
                                                  mb1n, mb2n, scale,
                                                  Zpart, Mpack);
    finalize4<<<dim3(NB / 16), 256, 0, stream>>>(Zpart, Mpack,
                                                 f1f, f2f, mb1, mb2, scale,
                                                 accum, out);
}